// Round 9
// baseline (246.252 us; speedup 1.0000x reference)
//
#include <hip/hip_runtime.h>

// CausalSelfAttention B=4, N=2048, D=1024, scale 1/32.
// prep (f32->f16 conv + W transpose) -> fused QKV GEMM (128x128, BK=64,
// VGPR-prefetch staging) -> S=QK^T 128x128 (per-tile max-subtracted exp,
// P + M/L) -> PV 128x128 swapped (C[d][q] = Vt . P^T, combine folded in).
//
// R19 (resubmitted R20 after container-acquisition failure; kernel never
// ran): QKV staging switched global_load_lds -> buffer_load->VGPR->ds_write
// (the S/PV pattern). Evidence: R11 header's prior-session finding ("~2.9
// B/cyc/block under every structure => ~1 outstanding global_load_lds per
// wave; VGPR-path loads fly concurrently") + cycle model: QKV per K-iter =
// 1750 cyc vs 620 MFMA floor; 8 gload_lds/wave/iter x ~200cyc serialized
// ~= 1600 cyc = the gap. Also retro-explains R12/R13 8-phase failures
// (2-3 gload_lds per phase = same serialization). S/PV/prep unchanged
// from R18. Numerics identical (exact two-stage flash softmax).

typedef __attribute__((ext_vector_type(8))) _Float16 half8;
typedef __attribute__((ext_vector_type(4))) _Float16 half4v;
typedef __attribute__((ext_vector_type(4))) float floatx4;

// ------------------------------------------------------------- merged prep
// blocks [0,8192): x f32->f16; [8192,11264): W transpose (32x32 tiles).
__global__ __launch_bounds__(256)
void prep(const float* __restrict__ in, _Float16* __restrict__ out,
          const float* __restrict__ W0, const float* __restrict__ W1,
          const float* __restrict__ W2, _Float16* __restrict__ Wt) {
  const int bid = blockIdx.x;
  if (bid < 8192) {
    const int i = (bid * 256 + threadIdx.x) << 2;
    float4 v = *(const float4*)(in + i);
    half4v o = { (_Float16)v.x, (_Float16)v.y, (_Float16)v.z, (_Float16)v.w };
    *(half4v*)(out + i) = o;
  } else {
    const int t = bid - 8192;              // 0..3071
    const int bz = t >> 10;                // 0..2
    const int rem = t & 1023;
    const int bx = rem & 31, by = rem >> 5;
    const float* W = bz == 0 ? W0 : (bz == 1 ? W1 : W2);
    _Float16* o = Wt + (long long)bz * 1048576;
    __shared__ _Float16 tl[32][33];
    const int tx = threadIdx.x & 31, ty = threadIdx.x >> 5;  // 32x8
    const int n0 = bx << 5, k0 = by << 5;
#pragma unroll
    for (int i = 0; i < 4; ++i)
      tl[ty + i * 8][tx] = (_Float16)W[(long long)(k0 + ty + i * 8) * 1024 + n0 + tx];
    __syncthreads();
#pragma unroll
    for (int i = 0; i < 4; ++i)
      o[(long long)(n0 + ty + i * 8) * 1024 + k0 + tx] = tl[tx][ty + i * 8];
  }
}

// ---------------------------------------------------------------- QKV GEMM
// 128x128 tile, BK=64, 4 waves 2x2; VGPR-prefetch staging (S/PV pattern):
// ds_write(tile k) | barrier | load(tile k+1 -> regs) | MFMA(tile k).
__global__ __launch_bounds__(256)
void gemm_qkv(const _Float16* __restrict__ A, const _Float16* __restrict__ B,
              _Float16* __restrict__ Q, _Float16* __restrict__ Kh,
              _Float16* __restrict__ Vt) {
  const int bm = blockIdx.y, bn = blockIdx.x;
  const _Float16* Ab = A + (long long)bm * 128 * 1024;
  const _Float16* Bb = B + (long long)bn * 128 * 1024;

  __shared__ _Float16 As[128][64];
  __shared__ _Float16 Bs[128][64];

  const int tid = threadIdx.x;
  const int wave = tid >> 6, lane = tid & 63;
  const int quad = lane >> 4, lr = lane & 15;
  const int wm = (wave >> 1) << 6, wn = (wave & 1) << 6;
  const int srow = lane >> 3;
  const int schunk = lane & 7;                 // LDS slot this lane fills
  const int goff = (schunk ^ srow) << 3;       // global chunk -> slot^(r&7)

  floatx4 acc[4][4] = {};
  const _Float16* ga = Ab + (long long)(wave * 8 + srow) * 1024 + goff;
  const _Float16* gb = Bb + (long long)(wave * 8 + srow) * 1024 + goff;

  half8 pa[4], pb[4];
#pragma unroll
  for (int c = 0; c < 4; ++c) {
    pa[c] = *(const half8*)(ga + c * 32 * 1024);
    pb[c] = *(const half8*)(gb + c * 32 * 1024);
  }

  for (int it = 0; it < 16; ++it) {
    __syncthreads();
#pragma unroll
    for (int c = 0; c < 4; ++c) {
      *(half8*)&As[wave * 8 + 32 * c + srow][schunk << 3] = pa[c];
      *(half8*)&Bs[wave * 8 + 32 * c + srow][schunk << 3] = pb[c];
    }
    __syncthreads();
    if (it + 1 < 16) {
      const int k1 = (it + 1) << 6;
#pragma unroll
      for (int c = 0; c < 4; ++c) {
        pa[c] = *(const half8*)(ga + c * 32 * 1024 + k1);
        pb[c] = *(const half8*)(gb + c * 32 * 1024 + k1);
      }
    }

#pragma unroll
    for (int kk = 0; kk < 2; ++kk) {
      half8 af[4], bf[4];
#pragma unroll
      for (int i = 0; i < 4; ++i) {
        const int ra = wm + (i << 4) + lr;
        const int rb = wn + (i << 4) + lr;
        af[i] = *(const half8*)&As[ra][(((kk << 2) + quad) ^ (ra & 7)) << 3];
        bf[i] = *(const half8*)&Bs[rb][(((kk << 2) + quad) ^ (rb & 7)) << 3];
      }
#pragma unroll
      for (int i = 0; i < 4; ++i)
#pragma unroll
        for (int j = 0; j < 4; ++j)
          acc[i][j] = __builtin_amdgcn_mfma_f32_16x16x32_f16(af[i], bf[j], acc[i][j], 0, 0, 0);
    }
  }

  const int colb = bn * 128 + wn + lr;
  const int rowb = bm * 128 + wm + (quad << 2);

  if (bn < 16) {
    _Float16* C = (bn < 8) ? Q : Kh;
    const int cb = colb & 1023;
#pragma unroll
    for (int i = 0; i < 4; ++i)
#pragma unroll
      for (int j = 0; j < 4; ++j)
#pragma unroll
        for (int r = 0; r < 4; ++r)
          C[(long long)(rowb + (i << 4) + r) * 1024 + cb + (j << 4)] =
              (_Float16)acc[i][j][r];
  } else {
    const int b = rowb >> 11;
    const int tb = rowb & 2047;
#pragma unroll
    for (int i = 0; i < 4; ++i) {
      const int tok = tb + (i << 4);
#pragma unroll
      for (int j = 0; j < 4; ++j) {
        const int d = (colb & 1023) + (j << 4);
        half4v v = { (_Float16)acc[i][j][0], (_Float16)acc[i][j][1],
                     (_Float16)acc[i][j][2], (_Float16)acc[i][j][3] };
        *(half4v*)&Vt[(long long)b * 2097152 + (long long)d * 2048 + tok] = v;
      }
    }
  }
}

// ---------------------------------------------------------------- S GEMM
// P[128 q x 128 k] = exp(mask(Q K^T/32) - m_tile) f16 in (0,1];
// per-tile row max M and row sum L, cross-wave combined via LDS.
// Triangular grid bn <= bm (136/batch) + XCD swizzle (8x17).
__global__ __launch_bounds__(256)
void gemm_s_exp(const _Float16* __restrict__ Q, const _Float16* __restrict__ Kh,
                _Float16* __restrict__ P, float* __restrict__ M,
                float* __restrict__ L) {
  // 136 = 8*17: 17 consecutive triangular ids per XCD -> same-bm blocks
  // (sharing the Q panel) co-reside in one XCD's L2.
  int t = (blockIdx.x & 7) * 17 + (blockIdx.x >> 3);
  int bm = 0;
  for (;;) { const int c = bm + 1; if (t < c) break; t -= c; ++bm; }
  const int bn = t;
  const int bz = blockIdx.y;

  const _Float16* Ab = Q  + (long long)bz * 2097152 + (long long)bm * 128 * 1024;
  const _Float16* Bb = Kh + (long long)bz * 2097152 + (long long)bn * 128 * 1024;

  __shared__ _Float16 As[128][64];
  __shared__ _Float16 Bs[128][64];
  __shared__ float sm_m[2][2][64];   // [wm-half][wn-half][local row]
  __shared__ float sm_s[2][2][64];

  const int tid = threadIdx.x;
  const int wave = tid >> 6, lane = tid & 63;
  const int quad = lane >> 4, lr = lane & 15;
  const int wm = (wave >> 1) << 6, wn = (wave & 1) << 6;
  const int wm1 = wave >> 1, wn1 = wave & 1;
  const int srow = lane >> 3;
  const int schunk = lane & 7;                 // LDS slot this lane fills
  const int goff = (schunk ^ srow) << 3;       // global chunk -> slot^(r&7)

  floatx4 acc[4][4] = {};
  const _Float16* ga = Ab + (long long)(wave * 8 + srow) * 1024 + goff;
  const _Float16* gb = Bb + (long long)(wave * 8 + srow) * 1024 + goff;

  half8 pa[4], pb[4];
#pragma unroll
  for (int c = 0; c < 4; ++c) {
    pa[c] = *(const half8*)(ga + c * 32 * 1024);
    pb[c] = *(const half8*)(gb + c * 32 * 1024);
  }

  for (int it = 0; it < 16; ++it) {
    __syncthreads();
#pragma unroll
    for (int c = 0; c < 4; ++c) {
      *(half8*)&As[wave * 8 + 32 * c + srow][schunk << 3] = pa[c];
      *(half8*)&Bs[wave * 8 + 32 * c + srow][schunk << 3] = pb[c];
    }
    __syncthreads();
    if (it + 1 < 16) {
      const int k1 = (it + 1) << 6;
#pragma unroll
      for (int c = 0; c < 4; ++c) {
        pa[c] = *(const half8*)(ga + c * 32 * 1024 + k1);
        pb[c] = *(const half8*)(gb + c * 32 * 1024 + k1);
      }
    }

#pragma unroll
    for (int kk = 0; kk < 2; ++kk) {
      half8 af[4], bf[4];
#pragma unroll
      for (int i = 0; i < 4; ++i) {
        const int ra = wm + (i << 4) + lr;
        const int rb = wn + (i << 4) + lr;
        af[i] = *(const half8*)&As[ra][(((kk << 2) + quad) ^ (ra & 7)) << 3];
        bf[i] = *(const half8*)&Bs[rb][(((kk << 2) + quad) ^ (rb & 7)) << 3];
      }
#pragma unroll
      for (int i = 0; i < 4; ++i)
#pragma unroll
        for (int j = 0; j < 4; ++j)
          acc[i][j] = __builtin_amdgcn_mfma_f32_16x16x32_f16(af[i], bf[j], acc[i][j], 0, 0, 0);
    }
  }

  // ---- epilogue: per-wave masked max -> cross-wn combine -> exp -> sums ->
  // single-writer M/L (wn1==0 wave).
  const int colb = bn * 128 + wn + lr;
  const int rowb = bm * 128 + wm + (quad << 2);
  _Float16* Pb = P + (long long)bz * 4194304;
  const float scl = 0.03125f;

  float mx[4][4], rs[4][4];
#pragma unroll
  for (int i = 0; i < 4; ++i)
#pragma unroll
    for (int r = 0; r < 4; ++r) { mx[i][r] = -3.0e38f; rs[i][r] = 0.f; }

#pragma unroll
  for (int i = 0; i < 4; ++i)
#pragma unroll
    for (int j = 0; j < 4; ++j)
#pragma unroll
      for (int r = 0; r < 4; ++r) {
        const int qr = rowb + (i << 4) + r;
        const int kcol = colb + (j << 4);
        if (kcol <= qr) mx[i][r] = fmaxf(mx[i][r], acc[i][j][r] * scl);
      }
#pragma unroll
  for (int i = 0; i < 4; ++i)
#pragma unroll
    for (int r = 0; r < 4; ++r) {
#pragma unroll
      for (int off = 1; off < 16; off <<= 1)
        mx[i][r] = fmaxf(mx[i][r], __shfl_xor(mx[i][r], off));
    }

  if (lr == 0) {
#pragma unroll
    for (int i = 0; i < 4; ++i)
#pragma unroll
      for (int r = 0; r < 4; ++r)
        sm_m[wm1][wn1][(i << 4) + (quad << 2) + r] = mx[i][r];
  }
  __syncthreads();
  float mt[4][4];
#pragma unroll
  for (int i = 0; i < 4; ++i)
#pragma unroll
    for (int r = 0; r < 4; ++r)
      mt[i][r] = fmaxf(mx[i][r], sm_m[wm1][wn1 ^ 1][(i << 4) + (quad << 2) + r]);

#pragma unroll
  for (int i = 0; i < 4; ++i)
#pragma unroll
    for (int j = 0; j < 4; ++j)
#pragma unroll
      for (int r = 0; r < 4; ++r) {
        const int qr = rowb + (i << 4) + r;
        const int kcol = colb + (j << 4);
        const float pv =
            (kcol <= qr) ? __expf(acc[i][j][r] * scl - mt[i][r]) : 0.f;
        Pb[(long long)qr * 2048 + kcol] = (_Float16)pv;
        rs[i][r] += pv;
      }

#pragma unroll
  for (int i = 0; i < 4; ++i)
#pragma unroll
    for (int r = 0; r < 4; ++r) {
#pragma unroll
      for (int off = 1; off < 16; off <<= 1)
        rs[i][r] += __shfl_xor(rs[i][r], off);
    }

  if (lr == 0) {
#pragma unroll
    for (int i = 0; i < 4; ++i)
#pragma unroll
      for (int r = 0; r < 4; ++r)
        sm_s[wm1][wn1][(i << 4) + (quad << 2) + r] = rs[i][r];
  }
  __syncthreads();
  if (wn1 == 0 && lr == 0) {
    float* Mb = M + ((long long)bz * 16 + bn) * 2048;
    float* Lb = L + ((long long)bz * 16 + bn) * 2048;
#pragma unroll
    for (int i = 0; i < 4; ++i)
#pragma unroll
      for (int r = 0; r < 4; ++r) {
        const int lrow = (i << 4) + (quad << 2) + r;
        const int row = rowb + (i << 4) + r;
        Mb[row] = mt[i][r];
        Lb[row] = rs[i][r] + sm_s[wm1][1][lrow];
      }
  }
}

// ---------------------------------------------------------------- PV GEMM
// Swapped: C[128 d x 128 q] = Vt_panel . P_panel^T; out[q][d] = C^T * 1/l.
// A = Vt (rows d, ld 2048), B = P (rows q, ld 2048, F-scaled at staging).
// Prologue folds combine: per-row m_g/F/1/l from M/L into LDS (no F/lg bufs).
// XCD map: 4 bm-groups ({15,14,1,0}...{9,8,7,6}, each sum(bm+1)=34, heavy
// pair first) x 2 dn-halves; Keff = 128*(bm+1).
__global__ __launch_bounds__(256)
void gemm_pv(const _Float16* __restrict__ P, const _Float16* __restrict__ Vt,
             const float* __restrict__ M, const float* __restrict__ L,
             float* __restrict__ out) {
  const int lid = blockIdx.x + (blockIdx.y << 3) + (blockIdx.z << 7);
  const int xcd = lid & 7;
  const int s = lid >> 3;              // 0..63
  const int p = s >> 4;                // 0..3 (heavy-first within group)
  const int dnl = (s >> 2) & 3;
  const int bz = s & 3;
  const int bmg = xcd >> 1, dng = xcd & 1;
  const int bm = (p < 2) ? (15 - 2 * bmg - p) : (2 * bmg + (3 - p));
  const int dn = dng * 4 + dnl;
  const int niter = 2 * (bm + 1);      // Keff/64

  const _Float16* Ab = Vt + (long long)bz * 2097152 + (long long)dn * 128 * 2048;
  const _Float16* Bb = P  + (long long)bz * 4194304 + (long long)bm * 128 * 2048;

  __shared__ _Float16 As[128][64];
  __shared__ _Float16 Bs[128][64];
  __shared__ float F_lds[16][128];
  __shared__ float linv_lds[128];

  const int tid = threadIdx.x;
  const int wave = tid >> 6, lane = tid & 63;
  const int quad = lane >> 4, lr = lane & 15;
  const int wm = (wave >> 1) << 6, wn = (wave & 1) << 6;
  const int srow = lane >> 3;
  const int schunk = lane & 7;
  const int goff = (schunk ^ srow) << 3;
  const int lrow0 = wave * 8 + srow;   // tile-local staged row, chunk c: +32c

  // ---- folded combine: rows q_local = tid (<128) of this bm-panel ----
  if (tid < 128) {
    const float* Mb = M + (long long)bz * 32768 + bm * 128 + tid;
    const float* Lb = L + (long long)bz * 32768 + bm * 128 + tid;
    float mg = -3.0e38f;
    for (int t = 0; t <= bm; ++t) mg = fmaxf(mg, Mb[t * 2048]);
    float ssum = 0.f;
    for (int t = 0; t <= bm; ++t) {
      const float f = __expf(Mb[t * 2048] - mg);
      F_lds[t][tid] = f;
      ssum += f * Lb[t * 2048];
    }
    linv_lds[tid] = 1.0f / ssum;
  }

  floatx4 acc[4][4] = {};
  const _Float16* ga = Ab + (long long)lrow0 * 2048 + goff;
  const _Float16* gb = Bb + (long long)lrow0 * 2048 + goff;

  half8 pa[4], pb[4];
#pragma unroll
  for (int c = 0; c < 4; ++c) {
    pa[c] = *(const half8*)(ga + (long long)c * 32 * 2048);
    pb[c] = *(const half8*)(gb + (long long)c * 32 * 2048);
  }

  for (int it = 0; it < niter; ++it) {
    __syncthreads();
    const int kt = it >> 1;
#pragma unroll
    for (int c = 0; c < 4; ++c) {
      *(half8*)&As[wave * 8 + 32 * c + srow][schunk << 3] = pa[c];
      *(half8*)&Bs[wave * 8 + 32 * c + srow][schunk << 3] =
          pb[c] * (_Float16)F_lds[kt][lrow0 + 32 * c];
    }
    __syncthreads();
    if (it + 1 < niter) {
      const int k1 = (it + 1) << 6;
#pragma unroll
      for (int c = 0; c < 4; ++c) {
        pa[c] = *(const half8*)(ga + (long long)c * 32 * 2048 + k1);
        pb[c] = *(const half8*)(gb + (long long)c * 32 * 2048 + k1);
      }
    }

#pragma unroll
    for (int kk = 0; kk < 2; ++kk) {
      half8 af[4], bf[4];
#pragma unroll
      for (int i = 0; i < 4; ++i) {
        const int ra = wm + (i << 4) + lr;
        const int rb = wn + (i << 4) + lr;
        af[i] = *(const half8*)&As[ra][(((kk << 2) + quad) ^ (ra & 7)) << 3];
        bf[i] = *(const half8*)&Bs[rb][(((kk << 2) + quad) ^ (rb & 7)) << 3];
      }
#pragma unroll
      for (int i = 0; i < 4; ++i)
#pragma unroll
        for (int j = 0; j < 4; ++j)
          acc[i][j] = __builtin_amdgcn_mfma_f32_16x16x32_f16(af[i], bf[j], acc[i][j], 0, 0, 0);
    }
  }

  // epilogue: C[d_local][q_local]; d_local = wm+16i+(quad<<2)+r (4 consec
  // regs = 4 consec d -> float4), q_local = wn+16j+lr.
  float* Cb = out + (long long)bz * 2097152;
  const int d0 = dn * 128 + wm + (quad << 2);
  const int q0 = bm * 128 + wn + lr;

  float linv[4];
#pragma unroll
  for (int j = 0; j < 4; ++j) linv[j] = linv_lds[wn + (j << 4) + lr];

#pragma unroll
  for (int i = 0; i < 4; ++i)
#pragma unroll
    for (int j = 0; j < 4; ++j) {
      float4 v = { acc[i][j][0] * linv[j], acc[i][j][1] * linv[j],
                   acc[i][j][2] * linv[j], acc[i][j][3] * linv[j] };
      *(float4*)&Cb[(long long)(q0 + (j << 4)) * 1024 + d0 + (i << 4)] = v;
    }
}

// ---------------------------------------------------------------- launch

extern "C" void kernel_launch(void* const* d_in, const int* in_sizes, int n_in,
                              void* d_out, int out_size, void* d_ws, size_t ws_size,
                              hipStream_t stream) {
  const float* x  = (const float*)d_in[0];
  const float* Wq = (const float*)d_in[1];
  const float* Wk = (const float*)d_in[2];
  const float* Wv = (const float*)d_in[3];
  float* out = (float*)d_out;

  char* ws = (char*)d_ws;
  _Float16* xh = (_Float16*)(ws);               // 8192x1024 f16   (16 MiB)
  _Float16* Wt = (_Float16*)(ws + 16777216);    // 3072x1024 f16   ( 6 MiB)
  _Float16* Q  = (_Float16*)(ws + 23068672);    // 8192x1024 f16
  _Float16* Kh = (_Float16*)(ws + 39845888);    // 8192x1024 f16
  _Float16* Vt = (_Float16*)(ws + 56623104);    // 4x1024x2048 f16
  _Float16* P  = (_Float16*)(ws + 73400320);    // 4x2048x2048 f16 (exp-m_tile)
  float*    M  = (float*)   (ws + 106954752);   // [4][16][2048] tile row max
  float*    L  = (float*)   (ws + 107479040);   // [4][16][2048] tile row sum

  // merged: x convert + W transpose
  prep<<<11264, 256, 0, stream>>>(x, xh, Wq, Wk, Wv, Wt);

  // fused QKV: [8192,1024] x [3072,1024]^T (VGPR-prefetch staging)
  gemm_qkv<<<dim3(24, 64), 256, 0, stream>>>(xh, Wt, Q, Kh, Vt);

  // P = exp(mask(Q K^T / 32) - m_tile), per-tile m/l; triangular grid
  gemm_s_exp<<<dim3(136, 4), 256, 0, stream>>>(Q, Kh, P, M, L);

  // out = (sum F*P V) / l_g; swapped operands, combine folded in
  gemm_pv<<<dim3(8, 16, 4), 256, 0, stream>>>(P, Vt, M, L, out);
}

// Round 11
// 229.729 us; speedup vs baseline: 1.0719x; 1.0719x over previous
//
#include <hip/hip_runtime.h>

// CausalSelfAttention B=4, N=2048, D=1024, scale 1/32.
// prep (f32->f16 conv + W transpose) -> fused QKV GEMM (128x128, BK=64,
// global_load_lds) -> S=QK^T 64x128 q-tiles (per-tile max-subtracted exp,
// P + M/L) -> PV 128x128 swapped (C[d][q] = Vt . P^T, combine folded in).
//
// R21 (resubmitted twice after container-acquisition failures; never ran):
// (a) QKV reverted to R18's global_load_lds kernel - R19 falsified the
// staging-serialization theory (VGPR-prefetch = 71.5us vs 69.9, MfmaUtil
// 30% both ways; the 128^2 2-phase structure is pinned ~736 TF). (b) S
// split 128x128 -> 64x128 q-tiles: S/PV run at ~260 TF vs QKV's 736 with
// the SAME inner loop; the only differing resource is blocks/CU (QKV 6,
// S 2.1, PV 2) - the 1-tile-slack prefetch pipeline needs other resident
// blocks to hide latency. S grid 544 -> 1088 (4.25/CU, LDS 25KB -> ~6
// resident). Triangular decode (bn, qm=2bn+t), M/L single-writer preserved,
// no fully-masked rows (qm >= 2bn). PV/prep unchanged from R18.

typedef __attribute__((ext_vector_type(8))) _Float16 half8;
typedef __attribute__((ext_vector_type(4))) _Float16 half4v;
typedef __attribute__((ext_vector_type(4))) float floatx4;

#define AS1 __attribute__((address_space(1)))
#define AS3 __attribute__((address_space(3)))

__device__ __forceinline__ void load16_lds(void* lds, const void* g) {
  __builtin_amdgcn_global_load_lds((AS1 void*)g, (AS3 void*)lds, 16, 0, 0);
}

// ------------------------------------------------------------- merged prep
// blocks [0,8192): x f32->f16; [8192,11264): W transpose (32x32 tiles).
__global__ __launch_bounds__(256)
void prep(const float* __restrict__ in, _Float16* __restrict__ out,
          const float* __restrict__ W0, const float* __restrict__ W1,
          const float* __restrict__ W2, _Float16* __restrict__ Wt) {
  const int bid = blockIdx.x;
  if (bid < 8192) {
    const int i = (bid * 256 + threadIdx.x) << 2;
    float4 v = *(const float4*)(in + i);
    half4v o = { (_Float16)v.x, (_Float16)v.y, (_Float16)v.z, (_Float16)v.w };
    *(half4v*)(out + i) = o;
  } else {
    const int t = bid - 8192;              // 0..3071
    const int bz = t >> 10;                // 0..2
    const int rem = t & 1023;
    const int bx = rem & 31, by = rem >> 5;
    const float* W = bz == 0 ? W0 : (bz == 1 ? W1 : W2);
    _Float16* o = Wt + (long long)bz * 1048576;
    __shared__ _Float16 tl[32][33];
    const int tx = threadIdx.x & 31, ty = threadIdx.x >> 5;  // 32x8
    const int n0 = bx << 5, k0 = by << 5;
#pragma unroll
    for (int i = 0; i < 4; ++i)
      tl[ty + i * 8][tx] = (_Float16)W[(long long)(k0 + ty + i * 8) * 1024 + n0 + tx];
    __syncthreads();
#pragma unroll
    for (int i = 0; i < 4; ++i)
      o[(long long)(n0 + ty + i * 8) * 1024 + k0 + tx] = tl[tx][ty + i * 8];
  }
}

// ---------------------------------------------------------------- QKV GEMM
// R18-exact (736 TF, conflicts 0): 128x128 tile, BK=64, 4 waves 2x2,
// global_load_lds staging.
__global__ __launch_bounds__(256)
void gemm_qkv(const _Float16* __restrict__ A, const _Float16* __restrict__ B,
              _Float16* __restrict__ Q, _Float16* __restrict__ Kh,
              _Float16* __restrict__ Vt) {
  const int bm = blockIdx.y, bn = blockIdx.x;
  const _Float16* Ab = A + (long long)bm * 128 * 1024;
  const _Float16* Bb = B + (long long)bn * 128 * 1024;

  __shared__ _Float16 As[128][64];
  __shared__ _Float16 Bs[128][64];

  const int tid = threadIdx.x;
  const int wave = tid >> 6, lane = tid & 63;
  const int quad = lane >> 4, lr = lane & 15;
  const int wm = (wave >> 1) << 6, wn = (wave & 1) << 6;
  const int srow = lane >> 3;
  const int goff = ((lane & 7) ^ srow) << 3;

  floatx4 acc[4][4] = {};
  const _Float16* ga = Ab + (long long)(wave * 8 + srow) * 1024 + goff;
  const _Float16* gb = Bb + (long long)(wave * 8 + srow) * 1024 + goff;

  for (int k0 = 0; k0 < 1024; k0 += 64) {
    __syncthreads();
#pragma unroll
    for (int c = 0; c < 4; ++c) {
      load16_lds(&As[wave * 8 + 32 * c][0], ga + c * 32 * 1024);
      load16_lds(&Bs[wave * 8 + 32 * c][0], gb + c * 32 * 1024);
    }
    ga += 64; gb += 64;
    __syncthreads();

#pragma unroll
    for (int kk = 0; kk < 2; ++kk) {
      half8 af[4], bf[4];
#pragma unroll
      for (int i = 0; i < 4; ++i) {
        const int ra = wm + (i << 4) + lr;
        const int rb = wn + (i << 4) + lr;
        af[i] = *(const half8*)&As[ra][(((kk << 2) + quad) ^ (ra & 7)) << 3];
        bf[i] = *(const half8*)&Bs[rb][(((kk << 2) + quad) ^ (rb & 7)) << 3];
      }
#pragma unroll
      for (int i = 0; i < 4; ++i)
#pragma unroll
        for (int j = 0; j < 4; ++j)
          acc[i][j] = __builtin_amdgcn_mfma_f32_16x16x32_f16(af[i], bf[j], acc[i][j], 0, 0, 0);
    }
  }

  const int colb = bn * 128 + wn + lr;
  const int rowb = bm * 128 + wm + (quad << 2);

  if (bn < 16) {
    _Float16* C = (bn < 8) ? Q : Kh;
    const int cb = colb & 1023;
#pragma unroll
    for (int i = 0; i < 4; ++i)
#pragma unroll
      for (int j = 0; j < 4; ++j)
#pragma unroll
        for (int r = 0; r < 4; ++r)
          C[(long long)(rowb + (i << 4) + r) * 1024 + cb + (j << 4)] =
              (_Float16)acc[i][j][r];
  } else {
    const int b = rowb >> 11;
    const int tb = rowb & 2047;
#pragma unroll
    for (int i = 0; i < 4; ++i) {
      const int tok = tb + (i << 4);
#pragma unroll
      for (int j = 0; j < 4; ++j) {
        const int d = (colb & 1023) + (j << 4);
        half4v v = { (_Float16)acc[i][j][0], (_Float16)acc[i][j][1],
                     (_Float16)acc[i][j][2], (_Float16)acc[i][j][3] };
        *(half4v*)&Vt[(long long)b * 2097152 + (long long)d * 2048 + tok] = v;
      }
    }
  }
}

// ---------------------------------------------------------------- S GEMM
// 64x128 q-tile: P[64 q x 128 k] = exp(mask(Q K^T/32) - m_tile) f16;
// per-tile row max M and row sum L (per 128-col K-tile, unchanged layout).
// 4 waves 2Mx2N (wm in {0,32}), VGPR-prefetch staging, 272 tiles/batch.
__global__ __launch_bounds__(256)
void gemm_s_exp(const _Float16* __restrict__ Q, const _Float16* __restrict__ Kh,
                _Float16* __restrict__ P, float* __restrict__ M,
                float* __restrict__ L) {
  // 272 = 8*34 XCD swizzle; decode (bn, qm): count per bn = 32-2bn, qm=2bn+t.
  int t = (blockIdx.x & 7) * 34 + (blockIdx.x >> 3);
  int bn = 0;
  for (;;) { const int c = 32 - 2 * bn; if (t < c) break; t -= c; ++bn; }
  const int qm = 2 * bn + t;           // 64-row q-tile index, 0..31
  const int bz = blockIdx.y;

  const _Float16* Ab = Q  + (long long)bz * 2097152 + (long long)qm * 64 * 1024;
  const _Float16* Bb = Kh + (long long)bz * 2097152 + (long long)bn * 128 * 1024;

  __shared__ _Float16 As[64][64];
  __shared__ _Float16 Bs[128][64];
  __shared__ float sm_m[2][2][32];   // [wm-half][wn-half][local row]
  __shared__ float sm_s[2][2][32];

  const int tid = threadIdx.x;
  const int wave = tid >> 6, lane = tid & 63;
  const int quad = lane >> 4, lr = lane & 15;
  const int wm1 = wave >> 1, wn1 = wave & 1;
  const int wm = wm1 << 5, wn = wn1 << 6;
  const int srow = lane >> 3;
  const int schunk = lane & 7;                 // LDS slot this lane fills
  const int goff = (schunk ^ srow) << 3;       // global chunk -> slot^(r&7)

  floatx4 acc[2][4] = {};
  const _Float16* ga = Ab + (long long)(wave * 8 + srow) * 1024 + goff;
  const _Float16* gb = Bb + (long long)(wave * 8 + srow) * 1024 + goff;

  half8 pa[2], pb[4];
#pragma unroll
  for (int c = 0; c < 2; ++c) pa[c] = *(const half8*)(ga + c * 32 * 1024);
#pragma unroll
  for (int c = 0; c < 4; ++c) pb[c] = *(const half8*)(gb + c * 32 * 1024);

  for (int it = 0; it < 16; ++it) {
    __syncthreads();
#pragma unroll
    for (int c = 0; c < 2; ++c)
      *(half8*)&As[wave * 8 + 32 * c + srow][schunk << 3] = pa[c];
#pragma unroll
    for (int c = 0; c < 4; ++c)
      *(half8*)&Bs[wave * 8 + 32 * c + srow][schunk << 3] = pb[c];
    __syncthreads();
    if (it + 1 < 16) {
      const int k1 = (it + 1) << 6;
#pragma unroll
      for (int c = 0; c < 2; ++c)
        pa[c] = *(const half8*)(ga + c * 32 * 1024 + k1);
#pragma unroll
      for (int c = 0; c < 4; ++c)
        pb[c] = *(const half8*)(gb + c * 32 * 1024 + k1);
    }

#pragma unroll
    for (int kk = 0; kk < 2; ++kk) {
      half8 af[2], bf[4];
#pragma unroll
      for (int i = 0; i < 2; ++i) {
        const int ra = wm + (i << 4) + lr;
        af[i] = *(const half8*)&As[ra][(((kk << 2) + quad) ^ (ra & 7)) << 3];
      }
#pragma unroll
      for (int j = 0; j < 4; ++j) {
        const int rb = wn + (j << 4) + lr;
        bf[j] = *(const half8*)&Bs[rb][(((kk << 2) + quad) ^ (rb & 7)) << 3];
      }
#pragma unroll
      for (int i = 0; i < 2; ++i)
#pragma unroll
        for (int j = 0; j < 4; ++j)
          acc[i][j] = __builtin_amdgcn_mfma_f32_16x16x32_f16(af[i], bf[j], acc[i][j], 0, 0, 0);
    }
  }

  // ---- epilogue: per-wave masked max -> cross-wn combine -> exp -> sums ->
  // single-writer M/L (wn1==0 wave). Rows: rowb + 16i + r, i<2 (32/wave).
  const int colb = bn * 128 + wn + lr;
  const int rowb = qm * 64 + wm + (quad << 2);
  _Float16* Pb = P + (long long)bz * 4194304;
  const float scl = 0.03125f;

  float mx[2][4], rs[2][4];
#pragma unroll
  for (int i = 0; i < 2; ++i)
#pragma unroll
    for (int r = 0; r < 4; ++r) { mx[i][r] = -3.0e38f; rs[i][r] = 0.f; }

#pragma unroll
  for (int i = 0; i < 2; ++i)
#pragma unroll
    for (int j = 0; j < 4; ++j)
#pragma unroll
      for (int r = 0; r < 4; ++r) {
        const int qr = rowb + (i << 4) + r;
        const int kcol = colb + (j << 4);
        if (kcol <= qr) mx[i][r] = fmaxf(mx[i][r], acc[i][j][r] * scl);
      }
#pragma unroll
  for (int i = 0; i < 2; ++i)
#pragma unroll
    for (int r = 0; r < 4; ++r) {
#pragma unroll
      for (int off = 1; off < 16; off <<= 1)
        mx[i][r] = fmaxf(mx[i][r], __shfl_xor(mx[i][r], off));
    }

  if (lr == 0) {
#pragma unroll
    for (int i = 0; i < 2; ++i)
#pragma unroll
      for (int r = 0; r < 4; ++r)
        sm_m[wm1][wn1][(i << 4) + (quad << 2) + r] = mx[i][r];
  }
  __syncthreads();
  float mt[2][4];
#pragma unroll
  for (int i = 0; i < 2; ++i)
#pragma unroll
    for (int r = 0; r < 4; ++r)
      mt[i][r] = fmaxf(mx[i][r], sm_m[wm1][wn1 ^ 1][(i << 4) + (quad << 2) + r]);

#pragma unroll
  for (int i = 0; i < 2; ++i)
#pragma unroll
    for (int j = 0; j < 4; ++j)
#pragma unroll
      for (int r = 0; r < 4; ++r) {
        const int qr = rowb + (i << 4) + r;
        const int kcol = colb + (j << 4);
        const float pv =
            (kcol <= qr) ? __expf(acc[i][j][r] * scl - mt[i][r]) : 0.f;
        Pb[(long long)qr * 2048 + kcol] = (_Float16)pv;
        rs[i][r] += pv;
      }

#pragma unroll
  for (int i = 0; i < 2; ++i)
#pragma unroll
    for (int r = 0; r < 4; ++r) {
#pragma unroll
      for (int off = 1; off < 16; off <<= 1)
        rs[i][r] += __shfl_xor(rs[i][r], off);
    }

  if (lr == 0) {
#pragma unroll
    for (int i = 0; i < 2; ++i)
#pragma unroll
      for (int r = 0; r < 4; ++r)
        sm_s[wm1][wn1][(i << 4) + (quad << 2) + r] = rs[i][r];
  }
  __syncthreads();
  if (wn1 == 0 && lr == 0) {
    float* Mb = M + ((long long)bz * 16 + bn) * 2048;
    float* Lb = L + ((long long)bz * 16 + bn) * 2048;
#pragma unroll
    for (int i = 0; i < 2; ++i)
#pragma unroll
      for (int r = 0; r < 4; ++r) {
        const int lrow = (i << 4) + (quad << 2) + r;
        const int row = rowb + (i << 4) + r;
        Mb[row] = mt[i][r];
        Lb[row] = rs[i][r] + sm_s[wm1][1][lrow];
      }
  }
}

// ---------------------------------------------------------------- PV GEMM
// Swapped: C[128 d x 128 q] = Vt_panel . P_panel^T; out[q][d] = C^T * 1/l.
// A = Vt (rows d, ld 2048), B = P (rows q, ld 2048, F-scaled at staging).
// Prologue folds combine: per-row m_g/F/1/l from M/L into LDS (no F/lg bufs).
// XCD map: 4 bm-groups ({15,14,1,0}...{9,8,7,6}, each sum(bm+1)=34, heavy
// pair first) x 2 dn-halves; Keff = 128*(bm+1).
__global__ __launch_bounds__(256)
void gemm_pv(const _Float16* __restrict__ P, const _Float16* __restrict__ Vt,
             const float* __restrict__ M, const float* __restrict__ L,
             float* __restrict__ out) {
  const int lid = blockIdx.x + (blockIdx.y << 3) + (blockIdx.z << 7);
  const int xcd = lid & 7;
  const int s = lid >> 3;              // 0..63
  const int p = s >> 4;                // 0..3 (heavy-first within group)
  const int dnl = (s >> 2) & 3;
  const int bz = s & 3;
  const int bmg = xcd >> 1, dng = xcd & 1;
  const int bm = (p < 2) ? (15 - 2 * bmg - p) : (2 * bmg + (3 - p));
  const int dn = dng * 4 + dnl;
  const int niter = 2 * (bm + 1);      // Keff/64

  const _Float16* Ab = Vt + (long long)bz * 2097152 + (long long)dn * 128 * 2048;
  const _Float16* Bb = P  + (long long)bz * 4194304 + (long long)bm * 128 * 2048;

  __shared__ _Float16 As[128][64];
  __shared__ _Float16 Bs[128][64];
  __shared__ float F_lds[16][128];
  __shared__ float linv_lds[128];

  const int tid = threadIdx.x;
  const int wave = tid >> 6, lane = tid & 63;
  const int quad = lane >> 4, lr = lane & 15;
  const int wm = (wave >> 1) << 6, wn = (wave & 1) << 6;
  const int srow = lane >> 3;
  const int schunk = lane & 7;
  const int goff = (schunk ^ srow) << 3;
  const int lrow0 = wave * 8 + srow;   // tile-local staged row, chunk c: +32c

  // ---- folded combine: rows q_local = tid (<128) of this bm-panel ----
  if (tid < 128) {
    const float* Mb = M + (long long)bz * 32768 + bm * 128 + tid;
    const float* Lb = L + (long long)bz * 32768 + bm * 128 + tid;
    float mg = -3.0e38f;
    for (int t = 0; t <= bm; ++t) mg = fmaxf(mg, Mb[t * 2048]);
    float ssum = 0.f;
    for (int t = 0; t <= bm; ++t) {
      const float f = __expf(Mb[t * 2048] - mg);
      F_lds[t][tid] = f;
      ssum += f * Lb[t * 2048];
    }
    linv_lds[tid] = 1.0f / ssum;
  }

  floatx4 acc[4][4] = {};
  const _Float16* ga = Ab + (long long)lrow0 * 2048 + goff;
  const _Float16* gb = Bb + (long long)lrow0 * 2048 + goff;

  half8 pa[4], pb[4];
#pragma unroll
  for (int c = 0; c < 4; ++c) {
    pa[c] = *(const half8*)(ga + (long long)c * 32 * 2048);
    pb[c] = *(const half8*)(gb + (long long)c * 32 * 2048);
  }

  for (int it = 0; it < niter; ++it) {
    __syncthreads();
    const int kt = it >> 1;
#pragma unroll
    for (int c = 0; c < 4; ++c) {
      *(half8*)&As[wave * 8 + 32 * c + srow][schunk << 3] = pa[c];
      *(half8*)&Bs[wave * 8 + 32 * c + srow][schunk << 3] =
          pb[c] * (_Float16)F_lds[kt][lrow0 + 32 * c];
    }
    __syncthreads();
    if (it + 1 < niter) {
      const int k1 = (it + 1) << 6;
#pragma unroll
      for (int c = 0; c < 4; ++c) {
        pa[c] = *(const half8*)(ga + (long long)c * 32 * 2048 + k1);
        pb[c] = *(const half8*)(gb + (long long)c * 32 * 2048 + k1);
      }
    }

#pragma unroll
    for (int kk = 0; kk < 2; ++kk) {
      half8 af[4], bf[4];
#pragma unroll
      for (int i = 0; i < 4; ++i) {
        const int ra = wm + (i << 4) + lr;
        const int rb = wn + (i << 4) + lr;
        af[i] = *(const half8*)&As[ra][(((kk << 2) + quad) ^ (ra & 7)) << 3];
        bf[i] = *(const half8*)&Bs[rb][(((kk << 2) + quad) ^ (rb & 7)) << 3];
      }
#pragma unroll
      for (int i = 0; i < 4; ++i)
#pragma unroll
        for (int j = 0; j < 4; ++j)
          acc[i][j] = __builtin_amdgcn_mfma_f32_16x16x32_f16(af[i], bf[j], acc[i][j], 0, 0, 0);
    }
  }

  // epilogue: C[d_local][q_local]; d_local = wm+16i+(quad<<2)+r (4 consec
  // regs = 4 consec d -> float4), q_local = wn+16j+lr.
  float* Cb = out + (long long)bz * 2097152;
  const int d0 = dn * 128 + wm + (quad << 2);
  const int q0 = bm * 128 + wn + lr;

  float linv[4];
#pragma unroll
  for (int j = 0; j < 4; ++j) linv[j] = linv_lds[wn + (j << 4) + lr];

#pragma unroll
  for (int i = 0; i < 4; ++i)
#pragma unroll
    for (int j = 0; j < 4; ++j) {
      float4 v = { acc[i][j][0] * linv[j], acc[i][j][1] * linv[j],
                   acc[i][j][2] * linv[j], acc[i][j][3] * linv[j] };
      *(float4*)&Cb[(long long)(q0 + (j << 4)) * 1024 + d0 + (i << 4)] = v;
    }
}

// ---------------------------------------------------------------- launch

extern "C" void kernel_launch(void* const* d_in, const int* in_sizes, int n_in,
                              void* d_out, int out_size, void* d_ws, size_t ws_size,
                              hipStream_t stream) {
  const float* x  = (const float*)d_in[0];
  const float* Wq = (const float*)d_in[1];
  const float* Wk = (const float*)d_in[2];
  const float* Wv = (const float*)d_in[3];
  float* out = (float*)d_out;

  char* ws = (char*)d_ws;
  _Float16* xh = (_Float16*)(ws);               // 8192x1024 f16   (16 MiB)
  _Float16* Wt = (_Float16*)(ws + 16777216);    // 3072x1024 f16   ( 6 MiB)
  _Float16* Q  = (_Float16*)(ws + 23068672);    // 8192x1024 f16
  _Float16* Kh = (_Float16*)(ws + 39845888);    // 8192x1024 f16
  _Float16* Vt = (_Float16*)(ws + 56623104);    // 4x1024x2048 f16
  _Float16* P  = (_Float16*)(ws + 73400320);    // 4x2048x2048 f16 (exp-m_tile)
  float*    M  = (float*)   (ws + 106954752);   // [4][16][2048] tile row max
  float*    L  = (float*)   (ws + 107479040);   // [4][16][2048] tile row sum

  // merged: x convert + W transpose
  prep<<<11264, 256, 0, stream>>>(x, xh, Wq, Wk, Wv, Wt);

  // fused QKV: [8192,1024] x [3072,1024]^T (global_load_lds staging)
  gemm_qkv<<<dim3(24, 64), 256, 0, stream>>>(xh, Wt, Q, Kh, Vt);

  // P = exp(mask(Q K^T / 32) - m_tile), per-tile m/l; 64x128 q-tiles
  gemm_s_exp<<<dim3(272, 4), 256, 0, stream>>>(Q, Kh, P, M, L);

  // out = (sum F*P V) / l_g; swapped operands, combine folded in
  gemm_pv<<<dim3(8, 16, 4), 256, 0, stream>>>(P, Vt, M, L, out);
}